// Round 13
// baseline (135.298 us; speedup 1.0000x reference)
//
#include <hip/hip_runtime.h>

// WaveNet single-output inference on MI355X — v7: native-math + fuseB parallel
// + in-kernel ablation variants (MODE1/2/3 write to dummy buffers; profiled
// as separate dispatches to locate fuseA's unexplained ~45us cost).
// Sparse tree: only skip_sum[:, :, 8190] matters; per-layer dependency
// positions form APs with stride dilation/2; h_12 never needed.

typedef __attribute__((ext_vector_type(8))) short short8;
typedef __attribute__((ext_vector_type(4))) float f32x4;

#define TLAST 8190
#define BATCH 32
#define MFMA(A, B, C) __builtin_amdgcn_mfma_f32_16x16x32_bf16(A, B, C, 0, 0, 0)

__device__ __forceinline__ ushort bf16hi(float x) {
    union { float f; uint u; } v; v.f = x;
    return (ushort)((v.u + 0x7fffu + ((v.u >> 16) & 1u)) >> 16);
}
__device__ __forceinline__ uint packsplit(float v) {
    const ushort h = bf16hi(v);
    const float hf = __uint_as_float((uint)h << 16);
    return (uint)h | ((uint)bf16hi(v - hf) << 16);
}
__device__ __forceinline__ float unpacksum(uint u) {
    return __uint_as_float(u << 16) + __uint_as_float(u & 0xffff0000u);
}
__device__ __forceinline__ int imin(int a, int b) { return a < b ? a : b; }
__device__ __forceinline__ short8 mk8(uint a, uint b, uint c, uint d) {
    union { uint4 v; short8 s; } u; u.v = make_uint4(a, b, c, d); return u.s;
}
__device__ __forceinline__ void rdrow(const uint* p, short8& mh, short8& mc) {
    const uint4 q0 = *(const uint4*)p;
    const uint4 q1 = *(const uint4*)(p + 4);
    mh = mk8((q0.x & 0xffffu) | (q0.y << 16), (q0.z & 0xffffu) | (q0.w << 16),
             (q1.x & 0xffffu) | (q1.y << 16), (q1.z & 0xffffu) | (q1.w << 16));
    mc = mk8((q0.x >> 16) | (q0.y & 0xffff0000u), (q0.z >> 16) | (q0.w & 0xffff0000u),
             (q1.x >> 16) | (q1.y & 0xffff0000u), (q1.z >> 16) | (q1.w & 0xffff0000u));
}

// tanh(f)*sigmoid(g) via native exp2/rcp only (no f32 division sequences)
__device__ __forceinline__ float act_native(float gate, float filt) {
    const float e1 = __builtin_amdgcn_exp2f(filt * 2.885390082f);    // e^{2f}
    const float th = 1.f - 2.f * __builtin_amdgcn_rcpf(e1 + 1.f);
    const float e2 = __builtin_amdgcn_exp2f(gate * -1.442695041f);   // e^{-g}
    return th * __builtin_amdgcn_rcpf(1.f + e2);
}

// ---- shared per-tile layer body. MODE 0 real; 1 no-act; 2 +hi-only MFMA;
// ---- 3 skeleton (no MFMA/weights, keeps LDS traffic + packs, data-dep alive)
template<int MODE>
__device__ __forceinline__ void layer_tile(
    const uint* __restrict__ Hi, uint* __restrict__ Ho,
    const ushort* __restrict__ pd, const ushort* __restrict__ pr,
    const float* __restrict__ db, const float* __restrict__ rb,
    float* __restrict__ gout, uint* __restrict__ sG,
    uint* __restrict__ expPtr, int expCnt,
    int tt, int nIn, int nOut, int sO, int aO, int bOff, int rmx,
    int lane, int nl, int o, int first, int doRes)
{
    const short8 z8 = {0,0,0,0,0,0,0,0};
    const int joF = tt * 16 + nl;
    const int j0 = imin(first ? joF : 2 * joF, nIn - 1);
    const int j1 = imin(first ? joF + 1 : 2 * joF + 2, nIn - 1);
    const bool zB = (aO + joF * sO + bOff) > rmx;

    short8 Ah[2], Al[2];
    rdrow(Hi + j0 * 36 + 8 * o, Ah[0], Al[0]);
    if (zB) { Ah[1] = z8; Al[1] = z8; }
    else    rdrow(Hi + j1 * 36 + 8 * o, Ah[1], Al[1]);

    f32x4 acc[4] = {{0,0,0,0},{0,0,0,0},{0,0,0,0},{0,0,0,0}};
    if (MODE <= 2) {
        #pragma unroll
        for (int kt = 0; kt < 2; ++kt)
            #pragma unroll
            for (int nt = 0; nt < 4; ++nt) {
                const int base = ((kt * 4 + nt) * 2) * 512 + lane * 8;
                const short8 Bh = *(const short8*)&pd[base];
                acc[nt] = MFMA(Ah[kt], Bh, acc[nt]);
                if (MODE <= 1) {
                    const short8 Bl = *(const short8*)&pd[base + 512];
                    acc[nt] = MFMA(Ah[kt], Bl, acc[nt]);
                    acc[nt] = MFMA(Al[kt], Bh, acc[nt]);
                }
            }
    } else {
        const float fb = (float)((short)Ah[0][0] + (short)Al[1][3]) * 1e-8f;
        #pragma unroll
        for (int nt = 0; nt < 4; ++nt) acc[nt] = (f32x4){fb, fb, fb, fb};
    }

    float dbg[2], dbf[2], rbv[2];
    #pragma unroll
    for (int nt = 0; nt < 2; ++nt) {
        dbg[nt] = db[nl + 16 * nt];
        dbf[nt] = db[nl + 16 * nt + 32];
        rbv[nt] = rb[nl + 16 * nt];
    }

    #pragma unroll
    for (int nt = 0; nt < 2; ++nt)
        #pragma unroll
        for (int r = 0; r < 4; ++r) {
            const float gate = acc[nt][r]     + dbg[nt];
            const float filt = acc[nt + 2][r] + dbf[nt];
            const float g = (MODE == 0) ? act_native(gate, filt)
                                        : 0.25f * gate + 0.25f * filt;
            const int ml = 4 * o + r, n = nl + 16 * nt;
            sG[ml * 36 + n] = packsplit(g);
            const int joG = tt * 16 + ml;
            if (joG < nOut && (aO + joG * sO) == TLAST) gout[n] = g;
        }

    if (doRes) {
        short8 gh, gl;
        rdrow(sG + nl * 36 + 8 * o, gh, gl);
        f32x4 accR[2] = {{0,0,0,0},{0,0,0,0}};
        if (MODE <= 2) {
            #pragma unroll
            for (int nt = 0; nt < 2; ++nt) {
                const int base = (nt * 2) * 512 + lane * 8;
                const short8 Rh = *(const short8*)&pr[base];
                accR[nt] = MFMA(gh, Rh, accR[nt]);
                if (MODE <= 1) {
                    const short8 Rl = *(const short8*)&pr[base + 512];
                    accR[nt] = MFMA(gh, Rl, accR[nt]);
                    accR[nt] = MFMA(gl, Rh, accR[nt]);
                }
            }
        } else {
            const float fb2 = (float)(short)gh[0] * 1e-8f;
            accR[0] = (f32x4){fb2, fb2, fb2, fb2};
            accR[1] = accR[0];
        }
        #pragma unroll
        for (int nt = 0; nt < 2; ++nt)
            #pragma unroll
            for (int r = 0; r < 4; ++r) {
                const int joE = tt * 16 + 4 * o + r;
                if (joE < nOut) {
                    const int jres = imin(first ? joE + 1 : 2 * joE + 1, nIn - 1);
                    const int n = nl + 16 * nt;
                    const float resv = unpacksum(Hi[jres * 36 + n]);
                    const uint pk = packsplit(accR[nt][r] + rbv[nt] + resv);
                    Ho[joE * 36 + n] = pk;
                    if (joE < expCnt) expPtr[joE * 32 + n] = pk;
                }
            }
    }
}

// ---------------------------------------------------------------- weight prep
__global__ __launch_bounds__(256) void wn_prep(
    const float* __restrict__ dil_w, const float* __restrict__ res_w,
    ushort* __restrict__ Wd, ushort* __restrict__ Wr)
{
    const int idx = blockIdx.x * 256 + threadIdx.x;
    if (idx < 12 * 4096) {
        const int l = idx >> 12, rem = idx & 4095, n = rem >> 6, k = rem & 63;
        const int kt = k >> 5, ic = k & 31, o = (k >> 3) & 3, r8 = k & 7;
        const int lane = o * 16 + (n & 15), nt = n >> 4;
        const float v = dil_w[((size_t)l * 64 + n) * 64 + 2 * ic + kt];
        const ushort h = bf16hi(v);
        const ushort lo = bf16hi(v - __uint_as_float((uint)h << 16));
        const int base = l * 8192 + ((kt * 4 + nt) * 2) * 512 + lane * 8 + r8;
        Wd[base] = h;
        Wd[base + 512] = lo;
    } else if (idx < 12 * 4096 + 12 * 1024) {
        const int j = idx - 12 * 4096;
        const int l = j >> 10, rem = j & 1023, n = rem >> 5, k = rem & 31;
        const int o = k >> 3, r8 = k & 7;
        const int lane = o * 16 + (n & 15), nt = n >> 4;
        const float v = res_w[j];
        const ushort h = bf16hi(v);
        const ushort lo = bf16hi(v - __uint_as_float((uint)h << 16));
        const int base = l * 2048 + (nt * 2) * 512 + lane * 8 + r8;
        Wr[base] = h;
        Wr[base + 512] = lo;
    }
}

// ---------------------------------------------------------------- phase A
// Grid (32, BATCH), 4 waves/block; block owns chunk cc. Pyramid 96->...->2.
template<int MODE>
__global__ __launch_bounds__(256) void wn_fuseA(
    const float* __restrict__ x, const float* __restrict__ in_w,
    const float* __restrict__ in_b,
    const ushort* __restrict__ Wd, const ushort* __restrict__ Wr,
    const float* __restrict__ dil_b, const float* __restrict__ res_b,
    uint* __restrict__ c6, float* __restrict__ gTL)
{
    __shared__ __align__(16) uint ping[96 * 36];
    __shared__ __align__(16) uint pong[95 * 36];
    __shared__ __align__(16) uint sG[4][16 * 36];
    float* xs = (float*)pong;

    const int tid = threadIdx.x, lane = tid & 63, w = tid >> 6;
    const int nl = lane & 15, o = lane >> 4;
    const int cc = blockIdx.x, b = blockIdx.y;
    const int t6a = 6174 + cc * 64, a0 = t6a - 31;

    for (int i = tid; i < 384; i += 256) {
        const int p = i >> 2, c4 = (i & 3) * 4;
        const int t = a0 + p;
        float4 v = make_float4(0.f, 0.f, 0.f, 0.f);
        if (t <= 8191) v = *(const float4*)&x[((size_t)b * 8192 + t) * 16 + c4];
        *(float4*)&xs[p * 20 + c4] = v;
    }
    __syncthreads();

    {
        const int c = tid & 31, pg = tid >> 5;
        float wr[16];
        #pragma unroll
        for (int f = 0; f < 16; ++f) wr[f] = in_w[c * 16 + f];
        const float bias = in_b[c];
        #pragma unroll
        for (int q = 0; q < 12; ++q) {
            const int p = pg + 8 * q;
            float acc = bias;
            #pragma unroll
            for (int f4 = 0; f4 < 4; ++f4) {
                const float4 xv = *(const float4*)&xs[p * 20 + f4 * 4];
                acc += wr[f4*4]*xv.x + wr[f4*4+1]*xv.y
                     + wr[f4*4+2]*xv.z + wr[f4*4+3]*xv.w;
            }
            ping[p * 36 + c] = packsplit(acc);
        }
    }
    __syncthreads();

    for (int l = 0; l < 6; ++l) {
        const uint* Hi = (l & 1) ? pong : ping;
        uint*       Ho = (l & 1) ? ping : pong;
        const int nIn  = (l == 0) ? 96 : (192 >> l) - 1;
        const int nOut = (192 >> (l + 1)) - 1;
        const int nT   = (nOut + 15) >> 4;
        const int sO   = 1 << l;
        const int aO   = a0 + sO - 1;
        const int bOff = (l == 0) ? 1 : (sO >> 1);
        const int rmx  = (l == 0) ? 8191 : TLAST;

        for (int tt = w; tt < nT; tt += 4)
            layer_tile<MODE>(Hi, Ho, Wd + (size_t)l * 8192, Wr + (size_t)l * 2048,
                             dil_b + l * 64, res_b + l * 32,
                             gTL + ((size_t)l * BATCH + b) * 32, sG[w],
                             c6 + ((size_t)b * 64 + cc * 2) * 32, (l == 5) ? 2 : 0,
                             tt, nIn, nOut, sO, aO, bOff, rmx,
                             lane, nl, o, (l == 0) ? 1 : 0, 1);
        __syncthreads();
    }
}

// ---------------------------------------------------------------- phase B
// Grid BATCH blocks, 4 waves: ll0 on waves 0-1; ll1-5 wave 0; head split 4 ways.
__global__ __launch_bounds__(256) void wn_fuseB(
    const uint* __restrict__ c6,
    const ushort* __restrict__ Wd, const ushort* __restrict__ Wr,
    const float* __restrict__ dil_b, const float* __restrict__ res_b,
    const float* __restrict__ gTL,
    const float* __restrict__ sw, const float* __restrict__ sb,
    const float* __restrict__ f1w, const float* __restrict__ f1b,
    const float* __restrict__ f2w, const float* __restrict__ f2b,
    float* __restrict__ out)
{
    __shared__ __align__(16) uint HA[64 * 36];
    __shared__ __align__(16) uint HB[32 * 36];
    __shared__ __align__(16) uint sG2[2][16 * 36];
    __shared__ float gcap[6 * 32];
    __shared__ float psum[4][32];
    __shared__ float hd[64];

    const int tid = threadIdx.x, lane = tid & 63, w = tid >> 6;
    const int nl = lane & 15, o = lane >> 4;
    const int b = blockIdx.x;

    for (int i = tid; i < 512; i += 256) {
        const int row = i >> 3, c4 = (i & 7) * 4;
        *(uint4*)&HA[row * 36 + c4] = *(const uint4*)&c6[((size_t)b * 64 + row) * 32 + c4];
    }
    __syncthreads();

    // ll=0 (l=6): two tiles on waves 0,1
    if (w < 2) {
        layer_tile<0>(HA, HB, Wd + 6 * 8192, Wr + 6 * 2048,
                      dil_b + 6 * 64, res_b + 6 * 32,
                      gcap, sG2[w], (uint*)nullptr, 0,
                      w, 64, 32, 64, 6206, 32, TLAST, lane, nl, o, 0, 1);
    }
    __syncthreads();

    // ll=1..5: wave 0, wave-private ping/pong (no barriers needed)
    if (w == 0) {
        for (int ll = 1; ll < 6; ++ll) {
            const int l = ll + 6;
            const uint* Hi = (ll & 1) ? HB : HA;
            uint*       Ho = (ll & 1) ? HA : HB;
            const int sO = 64 << ll;
            layer_tile<0>(Hi, Ho, Wd + (size_t)l * 8192, Wr + (size_t)l * 2048,
                          dil_b + l * 64, res_b + l * 32,
                          gcap + ll * 32, sG2[0], (uint*)nullptr, 0,
                          0, 64 >> ll, 32 >> ll, sO, 6142 + sO, sO >> 1, TLAST,
                          lane, nl, o, 0, (ll < 5) ? 1 : 0);
        }
    }
    __syncthreads();

    // head: wave w computes skip partials for layers 3w..3w+2
    if (lane < 32) {
        const int c = lane;
        float part = 0.f;
        #pragma unroll
        for (int j = 0; j < 3; ++j) {
            const int l2 = 3 * w + j;
            float a = sb[l2 * 32 + c];
            const float* swr = sw + l2 * 1024 + c * 32;
            const float* gv = (l2 < 6) ? (gTL + ((size_t)l2 * BATCH + b) * 32)
                                       : (gcap + (l2 - 6) * 32);
            #pragma unroll
            for (int ic = 0; ic < 32; ++ic) a += swr[ic] * gv[ic];
            part += a;
        }
        psum[w][c] = part;
    }
    __syncthreads();

    if (w == 0 && lane < 32)
        hd[lane] = fmaxf(psum[0][lane] + psum[1][lane] + psum[2][lane] + psum[3][lane], 0.f);
    if (w == 0 && lane < 32) {
        float z = f1b[lane];
        #pragma unroll
        for (int ic = 0; ic < 32; ++ic) z += f1w[lane * 32 + ic] * hd[ic];
        hd[32 + lane] = fmaxf(z, 0.f);
    }
    if (w == 0 && lane == 0) {
        float o2 = f2b[0];
        #pragma unroll
        for (int ic = 0; ic < 32; ++ic) o2 += f2w[ic] * hd[32 + ic];
        out[b] = o2;
    }
}

// ---------------------------------------------------------------- launch
extern "C" void kernel_launch(void* const* d_in, const int* in_sizes, int n_in,
                              void* d_out, int out_size, void* d_ws, size_t ws_size,
                              hipStream_t stream)
{
    const float* x      = (const float*)d_in[0];
    const float* in_w   = (const float*)d_in[1];
    const float* in_b   = (const float*)d_in[2];
    const float* dil_w  = (const float*)d_in[3];
    const float* dil_b  = (const float*)d_in[4];
    const float* skip_w = (const float*)d_in[5];
    const float* skip_b = (const float*)d_in[6];
    const float* res_w  = (const float*)d_in[7];
    const float* res_b  = (const float*)d_in[8];
    const float* f1_w   = (const float*)d_in[9];
    const float* f1_b   = (const float*)d_in[10];
    const float* f2_w   = (const float*)d_in[11];
    const float* f2_b   = (const float*)d_in[12];

    char* p = (char*)d_ws;
    ushort* Wd  = (ushort*)p; p += 12 * 8192 * 2;
    ushort* Wr  = (ushort*)p; p += 12 * 2048 * 2;
    uint*   c6  = (uint*)p;   p += 32 * 64 * 32 * 4;
    float*  gTL = (float*)p;  p += 12 * 32 * 32 * 4;
    uint*   c6d = (uint*)p;   p += 32 * 64 * 32 * 4;   // ablation dummies
    float*  gTLd = (float*)p;

    wn_prep<<<dim3(240), dim3(256), 0, stream>>>(dil_w, res_w, Wd, Wr);

    wn_fuseA<0><<<dim3(32, BATCH), dim3(256), 0, stream>>>(
        x, in_w, in_b, Wd, Wr, dil_b, res_b, c6, gTL);

    // ---- ablation variants (dummy outputs; profiled as separate dispatches)
    wn_fuseA<1><<<dim3(32, BATCH), dim3(256), 0, stream>>>(
        x, in_w, in_b, Wd, Wr, dil_b, res_b, c6d, gTLd);
    wn_fuseA<2><<<dim3(32, BATCH), dim3(256), 0, stream>>>(
        x, in_w, in_b, Wd, Wr, dil_b, res_b, c6d, gTLd);
    wn_fuseA<3><<<dim3(32, BATCH), dim3(256), 0, stream>>>(
        x, in_w, in_b, Wd, Wr, dil_b, res_b, c6d, gTLd);

    wn_fuseB<<<dim3(BATCH), dim3(256), 0, stream>>>(
        c6, Wd, Wr, dil_b, res_b, gTL,
        skip_w, skip_b, f1_w, f1_b, f2_w, f2_b, (float*)d_out);
}

// Round 14
// 76.782 us; speedup vs baseline: 1.7621x; 1.7621x over previous
//
#include <hip/hip_runtime.h>

// WaveNet single-output inference on MI355X — v8: tile-pair ILP.
// Sparse tree: only skip_sum[:, :, 8190] matters; per-layer dependency
// positions form APs with stride dilation/2; h_12 never needed.
// fuseA: block (4 waves) owns one chunk's in_conv + layers 0-5 pyramid
//        (96->95->47->23->11->5->2). Each wave now processes a PAIR of
//        tiles concurrently (2x ILP in the latency-bound tile chain):
//        all A/residual LDS reads issued up front, 60 MFMAs interleave two
//        independent acc chains. launch_bounds(256,1) keeps B in registers.
// fuseB: r13 structure (ll0 on 2 waves, ll1-5 wave 0, head split 4 ways).
// Numerics: r6-verified 3-term bf16 split (Ah.Bh + Ah.Bl + Al.Bh); H stored
// as packed u32 (h | lo<<16); act via native exp2/rcp. r13 passed absmax 0.

typedef __attribute__((ext_vector_type(8))) short short8;
typedef __attribute__((ext_vector_type(4))) float f32x4;

#define TLAST 8190
#define BATCH 32
#define MFMA(A, B, C) __builtin_amdgcn_mfma_f32_16x16x32_bf16(A, B, C, 0, 0, 0)

__device__ __forceinline__ ushort bf16hi(float x) {
    union { float f; uint u; } v; v.f = x;
    return (ushort)((v.u + 0x7fffu + ((v.u >> 16) & 1u)) >> 16);
}
__device__ __forceinline__ uint packsplit(float v) {
    const ushort h = bf16hi(v);
    const float hf = __uint_as_float((uint)h << 16);
    return (uint)h | ((uint)bf16hi(v - hf) << 16);
}
__device__ __forceinline__ float unpacksum(uint u) {
    return __uint_as_float(u << 16) + __uint_as_float(u & 0xffff0000u);
}
__device__ __forceinline__ int imin(int a, int b) { return a < b ? a : b; }
__device__ __forceinline__ short8 mk8(uint a, uint b, uint c, uint d) {
    union { uint4 v; short8 s; } u; u.v = make_uint4(a, b, c, d); return u.s;
}
__device__ __forceinline__ void rdrow(const uint* p, short8& mh, short8& mc) {
    const uint4 q0 = *(const uint4*)p;
    const uint4 q1 = *(const uint4*)(p + 4);
    mh = mk8((q0.x & 0xffffu) | (q0.y << 16), (q0.z & 0xffffu) | (q0.w << 16),
             (q1.x & 0xffffu) | (q1.y << 16), (q1.z & 0xffffu) | (q1.w << 16));
    mc = mk8((q0.x >> 16) | (q0.y & 0xffff0000u), (q0.z >> 16) | (q0.w & 0xffff0000u),
             (q1.x >> 16) | (q1.y & 0xffff0000u), (q1.z >> 16) | (q1.w & 0xffff0000u));
}
__device__ __forceinline__ float act_native(float gate, float filt) {
    const float e1 = __builtin_amdgcn_exp2f(filt * 2.885390082f);
    const float th = 1.f - 2.f * __builtin_amdgcn_rcpf(e1 + 1.f);
    const float e2 = __builtin_amdgcn_exp2f(gate * -1.442695041f);
    return th * __builtin_amdgcn_rcpf(1.f + e2);
}

// ---------------------------------------------------------------- weight prep
// Frag-major bf16 layout. dil element k = ic + 32*kt, lane = o*16+nl,
// frag (a,kt,nt): Wd[l*8192 + ((kt*4+nt)*2+a)*512 + lane*8 + (k&7)], a:0=h 1=lo.
// res: Wr[l*2048 + (nt*2+a)*512 + lane*8 + (k&7)].
__global__ __launch_bounds__(256) void wn_prep(
    const float* __restrict__ dil_w, const float* __restrict__ res_w,
    ushort* __restrict__ Wd, ushort* __restrict__ Wr)
{
    const int idx = blockIdx.x * 256 + threadIdx.x;
    if (idx < 12 * 4096) {
        const int l = idx >> 12, rem = idx & 4095, n = rem >> 6, k = rem & 63;
        const int kt = k >> 5, ic = k & 31, o = (k >> 3) & 3, r8 = k & 7;
        const int lane = o * 16 + (n & 15), nt = n >> 4;
        const float v = dil_w[((size_t)l * 64 + n) * 64 + 2 * ic + kt];
        const ushort h = bf16hi(v);
        const ushort lo = bf16hi(v - __uint_as_float((uint)h << 16));
        const int base = l * 8192 + ((kt * 4 + nt) * 2) * 512 + lane * 8 + r8;
        Wd[base] = h;
        Wd[base + 512] = lo;
    } else if (idx < 12 * 4096 + 12 * 1024) {
        const int j = idx - 12 * 4096;
        const int l = j >> 10, rem = j & 1023, n = rem >> 5, k = rem & 31;
        const int o = k >> 3, r8 = k & 7;
        const int lane = o * 16 + (n & 15), nt = n >> 4;
        const float v = res_w[j];
        const ushort h = bf16hi(v);
        const ushort lo = bf16hi(v - __uint_as_float((uint)h << 16));
        const int base = l * 2048 + (nt * 2) * 512 + lane * 8 + r8;
        Wr[base] = h;
        Wr[base + 512] = lo;
    }
}

// ---------------------------------------------------------------- phase A
// Grid (32, BATCH), 4 waves. Wave w handles tile pair {2w, min(2w+1,nT-1)}.
__global__ __launch_bounds__(256, 1) void wn_fuseA(
    const float* __restrict__ x, const float* __restrict__ in_w,
    const float* __restrict__ in_b,
    const ushort* __restrict__ Wd, const ushort* __restrict__ Wr,
    const float* __restrict__ dil_b, const float* __restrict__ res_b,
    uint* __restrict__ c6, float* __restrict__ gTL)
{
    __shared__ __align__(16) uint ping[96 * 36];
    __shared__ __align__(16) uint pong[95 * 36];
    __shared__ __align__(16) uint sG[4][16 * 36];
    float* xs = (float*)pong;

    const int tid = threadIdx.x, lane = tid & 63, w = tid >> 6;
    const int nl = lane & 15, o = lane >> 4;
    const int cc = blockIdx.x, b = blockIdx.y;
    const int t6a = 6174 + cc * 64, a0 = t6a - 31;
    const short8 z8 = {0, 0, 0, 0, 0, 0, 0, 0};

    // ---- stage x (96 pos x 16 ch fp32)
    for (int i = tid; i < 384; i += 256) {
        const int p = i >> 2, c4 = (i & 3) * 4;
        const int t = a0 + p;
        float4 v = make_float4(0.f, 0.f, 0.f, 0.f);
        if (t <= 8191) v = *(const float4*)&x[((size_t)b * 8192 + t) * 16 + c4];
        *(float4*)&xs[p * 20 + c4] = v;
    }
    __syncthreads();

    // ---- in_conv -> ping (packed)
    {
        const int c = tid & 31, pg = tid >> 5;
        float wr[16];
        #pragma unroll
        for (int f = 0; f < 16; ++f) wr[f] = in_w[c * 16 + f];
        const float bias = in_b[c];
        #pragma unroll
        for (int q = 0; q < 12; ++q) {
            const int p = pg + 8 * q;
            float acc = bias;
            #pragma unroll
            for (int f4 = 0; f4 < 4; ++f4) {
                const float4 xv = *(const float4*)&xs[p * 20 + f4 * 4];
                acc += wr[f4*4]*xv.x + wr[f4*4+1]*xv.y
                     + wr[f4*4+2]*xv.z + wr[f4*4+3]*xv.w;
            }
            ping[p * 36 + c] = packsplit(acc);
        }
    }
    __syncthreads();

    for (int l = 0; l < 6; ++l) {
        const uint* Hi = (l & 1) ? pong : ping;
        uint*       Ho = (l & 1) ? ping : pong;
        const int nIn  = (l == 0) ? 96 : (192 >> l) - 1;
        const int nOut = (192 >> (l + 1)) - 1;      // 95,47,23,11,5,2
        const int nT   = (nOut + 15) >> 4;
        const int sO   = 1 << l;
        const int aO   = a0 + sO - 1;
        const int bOff = (l == 0) ? 1 : (sO >> 1);
        const int rmx  = (l == 0) ? 8191 : TLAST;
        const int first = (l == 0);

        // ---- B frags once per layer (coalesced frag-major global)
        const ushort* pd = Wd + (size_t)l * 8192;
        const ushort* pr = Wr + (size_t)l * 2048;
        short8 Bh[4][2], Bl[4][2], Rh[2], Rl[2];
        #pragma unroll
        for (int nt = 0; nt < 4; ++nt)
            #pragma unroll
            for (int kt = 0; kt < 2; ++kt) {
                const int base = ((kt * 4 + nt) * 2) * 512 + lane * 8;
                Bh[nt][kt] = *(const short8*)&pd[base];
                Bl[nt][kt] = *(const short8*)&pd[base + 512];
            }
        #pragma unroll
        for (int nt = 0; nt < 2; ++nt) {
            const int base = (nt * 2) * 512 + lane * 8;
            Rh[nt] = *(const short8*)&pr[base];
            Rl[nt] = *(const short8*)&pr[base + 512];
        }
        float dbg[2], dbf[2], rbv[2];
        #pragma unroll
        for (int nt = 0; nt < 2; ++nt) {
            dbg[nt] = dil_b[l * 64 + nl + 16 * nt];
            dbf[nt] = dil_b[l * 64 + nl + 16 * nt + 32];
            rbv[nt] = res_b[l * 32 + nl + 16 * nt];
        }

        const int tt0 = 2 * w;
        if (tt0 < nT) {
            const int tt1 = (tt0 + 1 < nT) ? tt0 + 1 : tt0;   // dup when odd

            // ---- A reads for both tiles (issued together)
            const int joF0 = tt0 * 16 + nl, joF1 = tt1 * 16 + nl;
            const int j00 = imin(first ? joF0 : 2 * joF0, nIn - 1);
            const int j01 = imin(first ? joF0 + 1 : 2 * joF0 + 2, nIn - 1);
            const int j10 = imin(first ? joF1 : 2 * joF1, nIn - 1);
            const int j11 = imin(first ? joF1 + 1 : 2 * joF1 + 2, nIn - 1);
            const bool zB0 = (aO + joF0 * sO + bOff) > rmx;
            const bool zB1 = (aO + joF1 * sO + bOff) > rmx;

            short8 Ah0[2], Al0[2], Ah1[2], Al1[2];
            rdrow(Hi + j00 * 36 + 8 * o, Ah0[0], Al0[0]);
            rdrow(Hi + j10 * 36 + 8 * o, Ah1[0], Al1[0]);
            if (zB0) { Ah0[1] = z8; Al0[1] = z8; }
            else     rdrow(Hi + j01 * 36 + 8 * o, Ah0[1], Al0[1]);
            if (zB1) { Ah1[1] = z8; Al1[1] = z8; }
            else     rdrow(Hi + j11 * 36 + 8 * o, Ah1[1], Al1[1]);

            // ---- residual pre-reads for both tiles (independent b32s)
            float rs0[2][4], rs1[2][4];
            #pragma unroll
            for (int nt = 0; nt < 2; ++nt)
                #pragma unroll
                for (int r = 0; r < 4; ++r) {
                    const int n = nl + 16 * nt;
                    const int e0 = tt0 * 16 + 4 * o + r;
                    const int e1 = tt1 * 16 + 4 * o + r;
                    const int q0 = imin(first ? e0 + 1 : 2 * e0 + 1, nIn - 1);
                    const int q1 = imin(first ? e1 + 1 : 2 * e1 + 1, nIn - 1);
                    rs0[nt][r] = unpacksum(Hi[q0 * 36 + n]);
                    rs1[nt][r] = unpacksum(Hi[q1 * 36 + n]);
                }

            // ---- gate/filt GEMM: two interleaved acc chains (48 MFMAs)
            f32x4 acc0[4] = {{0,0,0,0},{0,0,0,0},{0,0,0,0},{0,0,0,0}};
            f32x4 acc1[4] = {{0,0,0,0},{0,0,0,0},{0,0,0,0},{0,0,0,0}};
            #pragma unroll
            for (int kt = 0; kt < 2; ++kt)
                #pragma unroll
                for (int nt = 0; nt < 4; ++nt) {
                    acc0[nt] = MFMA(Ah0[kt], Bh[nt][kt], acc0[nt]);
                    acc1[nt] = MFMA(Ah1[kt], Bh[nt][kt], acc1[nt]);
                    acc0[nt] = MFMA(Ah0[kt], Bl[nt][kt], acc0[nt]);
                    acc1[nt] = MFMA(Ah1[kt], Bl[nt][kt], acc1[nt]);
                    acc0[nt] = MFMA(Al0[kt], Bh[nt][kt], acc0[nt]);
                    acc1[nt] = MFMA(Al1[kt], Bh[nt][kt], acc1[nt]);
                }

            // ================= tile 0 back-half =================
            #pragma unroll
            for (int nt = 0; nt < 2; ++nt)
                #pragma unroll
                for (int r = 0; r < 4; ++r) {
                    const float g = act_native(acc0[nt][r] + dbg[nt],
                                               acc0[nt + 2][r] + dbf[nt]);
                    const int ml = 4 * o + r, n = nl + 16 * nt;
                    sG[w][ml * 36 + n] = packsplit(g);
                    const int joG = tt0 * 16 + ml;
                    if (joG < nOut && (aO + joG * sO) == TLAST)
                        gTL[((size_t)l * BATCH + b) * 32 + n] = g;
                }
            {
                short8 gh, gl;
                rdrow(sG[w] + nl * 36 + 8 * o, gh, gl);
                f32x4 aR[2] = {{0,0,0,0},{0,0,0,0}};
                #pragma unroll
                for (int nt = 0; nt < 2; ++nt) {
                    aR[nt] = MFMA(gh, Rh[nt], aR[nt]);
                    aR[nt] = MFMA(gh, Rl[nt], aR[nt]);
                    aR[nt] = MFMA(gl, Rh[nt], aR[nt]);
                }
                #pragma unroll
                for (int nt = 0; nt < 2; ++nt)
                    #pragma unroll
                    for (int r = 0; r < 4; ++r) {
                        const int joE = tt0 * 16 + 4 * o + r;
                        if (joE < nOut) {
                            const int n = nl + 16 * nt;
                            const uint pk = packsplit(aR[nt][r] + rbv[nt] + rs0[nt][r]);
                            Ho[joE * 36 + n] = pk;
                            if (l == 5 && joE < 2)
                                c6[((size_t)b * 64 + cc * 2 + joE) * 32 + n] = pk;
                        }
                    }
            }

            // ================= tile 1 back-half =================
            #pragma unroll
            for (int nt = 0; nt < 2; ++nt)
                #pragma unroll
                for (int r = 0; r < 4; ++r) {
                    const float g = act_native(acc1[nt][r] + dbg[nt],
                                               acc1[nt + 2][r] + dbf[nt]);
                    const int ml = 4 * o + r, n = nl + 16 * nt;
                    sG[w][ml * 36 + n] = packsplit(g);
                    const int joG = tt1 * 16 + ml;
                    if (joG < nOut && (aO + joG * sO) == TLAST)
                        gTL[((size_t)l * BATCH + b) * 32 + n] = g;
                }
            {
                short8 gh, gl;
                rdrow(sG[w] + nl * 36 + 8 * o, gh, gl);
                f32x4 aR[2] = {{0,0,0,0},{0,0,0,0}};
                #pragma unroll
                for (int nt = 0; nt < 2; ++nt) {
                    aR[nt] = MFMA(gh, Rh[nt], aR[nt]);
                    aR[nt] = MFMA(gh, Rl[nt], aR[nt]);
                    aR[nt] = MFMA(gl, Rh[nt], aR[nt]);
                }
                #pragma unroll
                for (int nt = 0; nt < 2; ++nt)
                    #pragma unroll
                    for (int r = 0; r < 4; ++r) {
                        const int joE = tt1 * 16 + 4 * o + r;
                        if (joE < nOut) {
                            const int n = nl + 16 * nt;
                            const uint pk = packsplit(aR[nt][r] + rbv[nt] + rs1[nt][r]);
                            Ho[joE * 36 + n] = pk;
                            if (l == 5 && joE < 2)
                                c6[((size_t)b * 64 + cc * 2 + joE) * 32 + n] = pk;
                        }
                    }
            }
        }
        __syncthreads();
    }
}

// ---------------------------------------------------------------- fuseB tile
__device__ __forceinline__ void layer_tile1(
    const uint* __restrict__ Hi, uint* __restrict__ Ho,
    const ushort* __restrict__ pd, const ushort* __restrict__ pr,
    const float* __restrict__ db, const float* __restrict__ rb,
    float* __restrict__ gout, uint* __restrict__ sG,
    int tt, int nIn, int nOut, int sO, int aO, int bOff,
    int lane, int nl, int o, int doRes)
{
    const short8 z8 = {0,0,0,0,0,0,0,0};
    const int joF = tt * 16 + nl;
    const int j0 = imin(2 * joF, nIn - 1);
    const int j1 = imin(2 * joF + 2, nIn - 1);
    const bool zB = (aO + joF * sO + bOff) > TLAST;

    short8 Ah[2], Al[2];
    rdrow(Hi + j0 * 36 + 8 * o, Ah[0], Al[0]);
    if (zB) { Ah[1] = z8; Al[1] = z8; }
    else    rdrow(Hi + j1 * 36 + 8 * o, Ah[1], Al[1]);

    f32x4 acc[4] = {{0,0,0,0},{0,0,0,0},{0,0,0,0},{0,0,0,0}};
    #pragma unroll
    for (int kt = 0; kt < 2; ++kt)
        #pragma unroll
        for (int nt = 0; nt < 4; ++nt) {
            const int base = ((kt * 4 + nt) * 2) * 512 + lane * 8;
            const short8 Bh = *(const short8*)&pd[base];
            const short8 Bl = *(const short8*)&pd[base + 512];
            acc[nt] = MFMA(Ah[kt], Bh, acc[nt]);
            acc[nt] = MFMA(Ah[kt], Bl, acc[nt]);
            acc[nt] = MFMA(Al[kt], Bh, acc[nt]);
        }

    float dbg[2], dbf[2], rbv[2];
    #pragma unroll
    for (int nt = 0; nt < 2; ++nt) {
        dbg[nt] = db[nl + 16 * nt];
        dbf[nt] = db[nl + 16 * nt + 32];
        rbv[nt] = rb[nl + 16 * nt];
    }

    #pragma unroll
    for (int nt = 0; nt < 2; ++nt)
        #pragma unroll
        for (int r = 0; r < 4; ++r) {
            const float g = act_native(acc[nt][r] + dbg[nt], acc[nt + 2][r] + dbf[nt]);
            const int ml = 4 * o + r, n = nl + 16 * nt;
            sG[ml * 36 + n] = packsplit(g);
            const int joG = tt * 16 + ml;
            if (joG < nOut && (aO + joG * sO) == TLAST) gout[n] = g;
        }

    if (doRes) {
        short8 gh, gl;
        rdrow(sG + nl * 36 + 8 * o, gh, gl);
        f32x4 aR[2] = {{0,0,0,0},{0,0,0,0}};
        #pragma unroll
        for (int nt = 0; nt < 2; ++nt) {
            const int base = (nt * 2) * 512 + lane * 8;
            const short8 Rh = *(const short8*)&pr[base];
            const short8 Rl = *(const short8*)&pr[base + 512];
            aR[nt] = MFMA(gh, Rh, aR[nt]);
            aR[nt] = MFMA(gh, Rl, aR[nt]);
            aR[nt] = MFMA(gl, Rh, aR[nt]);
        }
        #pragma unroll
        for (int nt = 0; nt < 2; ++nt)
            #pragma unroll
            for (int r = 0; r < 4; ++r) {
                const int joE = tt * 16 + 4 * o + r;
                if (joE < nOut) {
                    const int jres = imin(2 * joE + 1, nIn - 1);
                    const int n = nl + 16 * nt;
                    const float resv = unpacksum(Hi[jres * 36 + n]);
                    Ho[joE * 36 + n] = packsplit(aR[nt][r] + rbv[nt] + resv);
                }
            }
    }
}

// ---------------------------------------------------------------- phase B
__global__ __launch_bounds__(256) void wn_fuseB(
    const uint* __restrict__ c6,
    const ushort* __restrict__ Wd, const ushort* __restrict__ Wr,
    const float* __restrict__ dil_b, const float* __restrict__ res_b,
    const float* __restrict__ gTL,
    const float* __restrict__ sw, const float* __restrict__ sb,
    const float* __restrict__ f1w, const float* __restrict__ f1b,
    const float* __restrict__ f2w, const float* __restrict__ f2b,
    float* __restrict__ out)
{
    __shared__ __align__(16) uint HA[64 * 36];
    __shared__ __align__(16) uint HB[32 * 36];
    __shared__ __align__(16) uint sG2[2][16 * 36];
    __shared__ float gcap[6 * 32];
    __shared__ float psum[4][32];
    __shared__ float hd[64];

    const int tid = threadIdx.x, lane = tid & 63, w = tid >> 6;
    const int nl = lane & 15, o = lane >> 4;
    const int b = blockIdx.x;

    for (int i = tid; i < 512; i += 256) {
        const int row = i >> 3, c4 = (i & 7) * 4;
        *(uint4*)&HA[row * 36 + c4] = *(const uint4*)&c6[((size_t)b * 64 + row) * 32 + c4];
    }
    __syncthreads();

    if (w < 2) {
        layer_tile1(HA, HB, Wd + 6 * 8192, Wr + 6 * 2048,
                    dil_b + 6 * 64, res_b + 6 * 32,
                    gcap, sG2[w],
                    w, 64, 32, 64, 6206, 32, lane, nl, o, 1);
    }
    __syncthreads();

    if (w == 0) {
        for (int ll = 1; ll < 6; ++ll) {
            const int l = ll + 6;
            const uint* Hi = (ll & 1) ? HB : HA;
            uint*       Ho = (ll & 1) ? HA : HB;
            const int sO = 64 << ll;
            layer_tile1(Hi, Ho, Wd + (size_t)l * 8192, Wr + (size_t)l * 2048,
                        dil_b + l * 64, res_b + l * 32,
                        gcap + ll * 32, sG2[0],
                        0, 64 >> ll, 32 >> ll, sO, 6142 + sO, sO >> 1,
                        lane, nl, o, (ll < 5) ? 1 : 0);
        }
    }
    __syncthreads();

    if (lane < 32) {
        const int c = lane;
        float part = 0.f;
        #pragma unroll
        for (int j = 0; j < 3; ++j) {
            const int l2 = 3 * w + j;
            float a = sb[l2 * 32 + c];
            const float* swr = sw + l2 * 1024 + c * 32;
            const float* gv = (l2 < 6) ? (gTL + ((size_t)l2 * BATCH + b) * 32)
                                       : (gcap + (l2 - 6) * 32);
            #pragma unroll
            for (int ic = 0; ic < 32; ++ic) a += swr[ic] * gv[ic];
            part += a;
        }
        psum[w][c] = part;
    }
    __syncthreads();

    if (w == 0 && lane < 32)
        hd[lane] = fmaxf(psum[0][lane] + psum[1][lane] + psum[2][lane] + psum[3][lane], 0.f);
    if (w == 0 && lane < 32) {
        float z = f1b[lane];
        #pragma unroll
        for (int ic = 0; ic < 32; ++ic) z += f1w[lane * 32 + ic] * hd[ic];
        hd[32 + lane] = fmaxf(z, 0.f);
    }
    if (w == 0 && lane == 0) {
        float o2 = f2b[0];
        #pragma unroll
        for (int ic = 0; ic < 32; ++ic) o2 += f2w[ic] * hd[32 + ic];
        out[b] = o2;
    }
}

// ---------------------------------------------------------------- launch
extern "C" void kernel_launch(void* const* d_in, const int* in_sizes, int n_in,
                              void* d_out, int out_size, void* d_ws, size_t ws_size,
                              hipStream_t stream)
{
    const float* x      = (const float*)d_in[0];
    const float* in_w   = (const float*)d_in[1];
    const float* in_b   = (const float*)d_in[2];
    const float* dil_w  = (const float*)d_in[3];
    const float* dil_b  = (const float*)d_in[4];
    const float* skip_w = (const float*)d_in[5];
    const float* skip_b = (const float*)d_in[6];
    const float* res_w  = (const float*)d_in[7];
    const float* res_b  = (const float*)d_in[8];
    const float* f1_w   = (const float*)d_in[9];
    const float* f1_b   = (const float*)d_in[10];
    const float* f2_w   = (const float*)d_in[11];
    const float* f2_b   = (const float*)d_in[12];

    char* p = (char*)d_ws;
    ushort* Wd  = (ushort*)p; p += 12 * 8192 * 2;
    ushort* Wr  = (ushort*)p; p += 12 * 2048 * 2;
    uint*   c6  = (uint*)p;   p += 32 * 64 * 32 * 4;
    float*  gTL = (float*)p;

    wn_prep<<<dim3(240), dim3(256), 0, stream>>>(dil_w, res_w, Wd, Wr);

    wn_fuseA<<<dim3(32, BATCH), dim3(256), 0, stream>>>(
        x, in_w, in_b, Wd, Wr, dil_b, res_b, c6, gTL);

    wn_fuseB<<<dim3(BATCH), dim3(256), 0, stream>>>(
        c6, Wd, Wr, dil_b, res_b, gTL,
        skip_w, skip_b, f1_w, f1_b, f2_w, f2_b, (float*)d_out);
}